// Round 4
// baseline (94.414 us; speedup 1.0000x reference)
//
#include <hip/hip_runtime.h>
#include <math.h>

#define N_ATOMS 400
#define N_RES   100
#define DT      0.02f
#define PI_D    3.14159265358979323846
#define NBLK    100
#define NTHR    256

// Monotonic epoch barrier counter. Lives in a device global (zero-initialized
// at module load, NOT in the harness-poisoned workspace). Each launch adds
// exactly NBLK; never reset. A block with ticket t waits until the counter
// reaches (t/NBLK)*NBLK + NBLK, i.e. all NBLK blocks of ITS launch arrived.
// Launches are stream-serialized, so the counter is a multiple of NBLK at
// every launch boundary.
__device__ unsigned long long g_epoch = 0ULL;

// ---------- small float3 helpers ----------
struct V3 { float x, y, z; };
__device__ __forceinline__ V3 v3(float x, float y, float z) { V3 r{x,y,z}; return r; }
__device__ __forceinline__ V3 sub(V3 a, V3 b) { return v3(a.x-b.x, a.y-b.y, a.z-b.z); }
__device__ __forceinline__ V3 neg(V3 a) { return v3(-a.x, -a.y, -a.z); }
__device__ __forceinline__ V3 scale(V3 a, float s) { return v3(a.x*s, a.y*s, a.z*s); }
__device__ __forceinline__ float dot3(V3 a, V3 b) { return a.x*b.x + a.y*b.y + a.z*b.z; }
__device__ __forceinline__ V3 cross3(V3 a, V3 b) {
    return v3(a.y*b.z - a.z*b.y, a.z*b.x - a.x*b.z, a.x*b.y - a.y*b.x);
}
__device__ __forceinline__ float vnorm(V3 a) {
    float s = dot3(a, a);
    return s > 0.0f ? sqrtf(s) : 0.0f;   // safe_norm semantics
}
__device__ __forceinline__ V3 normalize3(V3 a) {
    float n = fmaxf(vnorm(a), 1e-12f);
    return scale(a, 1.0f/n);
}

// ---------- bin index helpers (uniform grids; argmin == nearest, clamped) ----------
__device__ __forceinline__ int clampi(int i, int lo, int hi) {
    return i < lo ? lo : (i > hi ? hi : i);
}
__device__ __forceinline__ int bin_dist(float d) {
    const float INV = (float)(137.0/14.9);     // linspace(1.0, 15.9, 138)
    return clampi((int)floorf((d - 1.0f)*INV + 0.5f), 0, 137);
}
__device__ __forceinline__ int bin_ang(float a) {
    const float C0  = (float)(PI_D/3.0 + 1.5*((PI_D - PI_D/3.0)/140.0));
    const float INV = (float)(140.0/(PI_D - PI_D/3.0));
    return clampi((int)floorf((a - C0)*INV + 0.5f), 0, 137);
}
__device__ __forceinline__ int bin_dih(float a) {
    const float C0  = (float)(-PI_D + 0.5*(2.0*PI_D/140.0));
    const float INV = (float)(140.0/(2.0*PI_D));
    return clampi((int)floorf((a - C0)*INV + 0.5f), 0, 139);
}

// ---------- bonded-term tables ----------
__constant__ int ANG_I[5][3]   = {{0,1,2},{1,2,0},{2,0,1},{0,1,3},{2,1,3}};
__constant__ int ANG_ACROSS[5] = {0,1,2,0,0};
__constant__ int DIH_I[5][4]   = {{2,0,1,2},{0,1,2,0},{1,2,0,1},{2,0,1,3},{3,1,2,0}};
__constant__ int DIH_ACROSS[5] = {3,1,2,3,1};

__device__ __forceinline__ V3 ldpos(const float* c, int res, int atom) {
    int k = (res*4 + atom)*3;
    return v3(c[k], c[k+1], c[k+2]);
}

// add force f for (res, atom) into this block's LDS force slot IF res == b
__device__ __forceinline__ void addOwn(float* sF, int b, int res, int atom, V3 f) {
    if (res == b) {
        atomicAdd(&sF[atom*3+0], f.x);
        atomicAdd(&sF[atom*3+1], f.y);
        atomicAdd(&sF[atom*3+2], f.z);
    }
}

// Block b evaluates bonded terms at r = b (which=0) and r = b-1 (which=1),
// keeping only contributions that land on residue b. Redundant 2x eval of
// cross-residue terms; total <= 20 tiny term-evals per block.
__device__ __forceinline__ void bonded_own(int u, int b, const float* sc,
                              const float* __restrict__ ffa, const float* __restrict__ ffdih,
                              const int* __restrict__ ia, const int* __restrict__ idh,
                              float* sF) {
    int e = u % 10, which = u / 10;
    int r = b - which;
    if (e < 5) {
        // -------- angles --------
        int across = ANG_ACROSS[e];
        bool valid = which ? (b >= 1 && across != 0)
                           : (across == 0 || b <= N_RES-2);
        if (!valid) return;
        int i1 = ANG_I[e][0], i2 = ANG_I[e][1], i3 = ANG_I[e][2];
        int o2 = (across == 2) ? 1 : 0;
        int o3 = (across != 0) ? 1 : 0;
        V3 p1 = ldpos(sc, r,     i1);
        V3 p2 = ldpos(sc, r+o2,  i2);
        V3 p3 = ldpos(sc, r+o3,  i3);
        V3 ba = sub(p1, p2);
        V3 bc = sub(p3, p2);
        float ban = vnorm(ba), bcn = vnorm(bc);
        float ca = dot3(ba, bc) / (ban*bcn);
        ca = fminf(1.0f, fmaxf(-1.0f, ca));
        float ang = acosf(ca);
        int ind = bin_ang(ang);
        int potr = (across == 2) ? r+1 : r;
        const float* row = ffa + (e*20 + ia[potr])*140;
        float f = 0.5f*(row[ind] - row[ind+2]);
        V3 cr = cross3(ba, bc);
        V3 fa = scale(normalize3(cross3(ba, cr)), f/ban);
        V3 fc = scale(normalize3(neg(cross3(bc, cr))), f/bcn);
        V3 fb = neg(v3(fa.x+fc.x, fa.y+fc.y, fa.z+fc.z));
        addOwn(sF, b, r,     i1, fa);
        addOwn(sF, b, r+o2,  i2, fb);
        addOwn(sF, b, r+o3,  i3, fc);
    } else {
        // -------- dihedrals --------
        int di = e - 5;
        bool valid = which ? (b >= 1) : (b <= N_RES-2);
        if (!valid) return;
        int across = DIH_ACROSS[di];
        int i1 = DIH_I[di][0], i2 = DIH_I[di][1], i3 = DIH_I[di][2], i4 = DIH_I[di][3];
        int o2 = (across == 3) ? 1 : 0;
        int o3 = (across >= 2) ? 1 : 0;
        int o4 = 1;
        V3 p1 = ldpos(sc, r,     i1);
        V3 p2 = ldpos(sc, r+o2,  i2);
        V3 p3 = ldpos(sc, r+o3,  i3);
        V3 p4 = ldpos(sc, r+o4,  i4);
        V3 ab = sub(p2, p1);
        V3 bc = sub(p3, p2);
        V3 cd = sub(p4, p3);
        V3 c1 = cross3(ab, bc);
        V3 c2 = cross3(bc, cd);
        float bcn = vnorm(bc);
        V3 cc = cross3(c1, c2);
        float y = dot3(cc, bc) / bcn;
        float x = dot3(c1, c2);
        float dih = atan2f(y, x);
        int ind = bin_dih(dih);
        int potr = (across == 1) ? r : r+1;
        const float* row = ffdih + (di*20 + idh[potr])*142;
        float f = 0.5f*(row[ind] - row[ind+2]);
        V3 fa = scale(normalize3(neg(c1)), f / vnorm(ab));
        V3 fd = scale(normalize3(c2),      f / vnorm(cd));
        float bsq = bcn*bcn;
        float t1 = dot3(ab, bc)/bsq;
        float t2 = dot3(cd, bc)/bsq;
        V3 fb = v3(-fa.x - t1*fa.x + t2*fd.x,
                   -fa.y - t1*fa.y + t2*fd.y,
                   -fa.z - t1*fa.z + t2*fd.z);
        V3 fc = v3(-fa.x - fb.x - fd.x,
                   -fa.y - fb.y - fd.y,
                   -fa.z - fb.z - fd.z);
        addOwn(sF, b, r,     i1, fa);
        addOwn(sF, b, r+o2,  i2, fb);
        addOwn(sF, b, r+o3,  i3, fc);
        addOwn(sF, b, r+o4,  i4, fd);
    }
}

// Force phase: bonded (threads 0..19) + pair (one wave per own atom, types
// prefetched in ty[7]); result accumulated in sF[12].
__device__ __forceinline__ void force_phase(int b, int tid, int lane, int wave,
                              const float* sc, float* sF, const int* ty,
                              const float* __restrict__ ffd, const float* __restrict__ ffa,
                              const float* __restrict__ ffdih, const int* __restrict__ ia,
                              const int* __restrict__ idh) {
    if (tid < 20) bonded_own(tid, b, sc, ffa, ffdih, ia, idh, sF);

    int j = b*4 + wave;
    float cx = sc[3*j], cy = sc[3*j+1], cz = sc[3*j+2];
    float fx = 0.0f, fy = 0.0f, fz = 0.0f;
    #pragma unroll
    for (int k = 0; k < 7; ++k) {
        int i = lane + 64*k;
        if (k < 6 || i < N_ATOMS) {
            float dx = cx - sc[3*i];
            float dy = cy - sc[3*i+1];
            float dz = cz - sc[3*i+2];
            float d2 = dx*dx + dy*dy + dz*dz;
            float d  = d2 > 0.0f ? sqrtf(d2) : 0.0f;
            int ind  = bin_dist(d);
            const float* row = ffd + ty[k]*140;
            float f = 0.5f*(row[ind] - row[ind+2]);
            float w = f / fmaxf(d, 0.01f);
            fx += w*dx; fy += w*dy; fz += w*dz;
        }
    }
    #pragma unroll
    for (int off = 32; off > 0; off >>= 1) {
        fx += __shfl_down(fx, off);
        fy += __shfl_down(fy, off);
        fz += __shfl_down(fz, off);
    }
    if (lane == 0) {
        atomicAdd(&sF[wave*3+0], fx);
        atomicAdd(&sF[wave*3+1], fy);
        atomicAdd(&sF[wave*3+2], fz);
    }
}

// Single fused kernel: both force phases + all integration, ONE dispatch.
// Phase 1 coords (c1 = cin + vin*DT) are computed redundantly by every block
// into LDS (elementwise, cheap) -> no init dispatch. The mid-step grid-wide
// sync is a hand-rolled epoch barrier + explicit agent-scope fences (the
// same release/writeback + acquire/invalidate a kernel boundary would do),
// so phase-2 staging uses plain coalesced float4 loads. ty[] and v1/a1
// stay in registers across the barrier.
__global__ void __launch_bounds__(NTHR)
sim_fused(const float* __restrict__ cin, const float* __restrict__ vin,
          const float* __restrict__ masses, const float* __restrict__ ffd,
          const float* __restrict__ ffa, const float* __restrict__ ffdih,
          const int* __restrict__ iflat, const int* __restrict__ ia,
          const int* __restrict__ idh, float* __restrict__ c2,
          float* __restrict__ out)
{
    __shared__ float sc[N_ATOMS*3];
    __shared__ float sF[12];
    const int tid  = threadIdx.x;
    const int b    = blockIdx.x;
    const int lane = tid & 63;
    const int wave = tid >> 6;
    const int j    = b*4 + wave;

    // pair types: step-invariant, prefetched once, kept across both phases
    int ty[7];
    #pragma unroll
    for (int k = 0; k < 7; ++k) {
        int i = lane + 64*k;
        ty[k] = (k < 6 || i < N_ATOMS) ? iflat[i*N_ATOMS + j] : 0;
    }

    // ---- phase 1: c1 for ALL atoms into LDS (float4-vectorized) ----
    for (int q = tid; q < 300; q += NTHR) {
        float4 cv = ((const float4*)cin)[q];
        float4 vv = ((const float4*)vin)[q];
        float4 r;
        r.x = cv.x + vv.x*DT; r.y = cv.y + vv.y*DT;
        r.z = cv.z + vv.z*DT; r.w = cv.w + vv.w*DT;
        ((float4*)sc)[q] = r;
    }
    if (tid < 12) sF[tid] = 0.0f;
    __syncthreads();

    force_phase(b, tid, lane, wave, sc, sF, ty, ffd, ffa, ffdih, ia, idh);
    __syncthreads();

    // ---- integrate step 1 (block-local; v/a stay in registers) ----
    float v1r = 0.0f, a1r = 0.0f, mr = 1.0f;
    if (tid < 12) {
        int t = b*12 + tid;
        mr  = masses[b*4 + tid/3];
        a1r = sF[tid] / mr;
        v1r = vin[t] + 0.5f*a1r*DT;                 // a_last = 0
        float cc = sc[t] + v1r*DT + 0.5f*a1r*DT*DT;
        c2[t] = cc;                                  // plain store
        sF[tid] = 0.0f;                              // reset for phase 2
    }

    // ---- grid barrier: release(writeback) -> epoch add -> spin -> acquire(inv) ----
    __syncthreads();   // drains vmcnt: all 12 c2 stores complete before release
    if (tid == 0) {
        __builtin_amdgcn_fence(__ATOMIC_RELEASE, "agent");
        unsigned long long t = __hip_atomic_fetch_add(&g_epoch, 1ULL,
                                  __ATOMIC_RELAXED, __HIP_MEMORY_SCOPE_AGENT);
        unsigned long long target = (t/NBLK)*NBLK + NBLK;
        long iters = 0;
        while (__hip_atomic_load(&g_epoch, __ATOMIC_RELAXED,
                                 __HIP_MEMORY_SCOPE_AGENT) < target) {
            __builtin_amdgcn_s_sleep(1);
            if (++iters > (1L << 24)) break;   // hang guard; never taken
        }
        __builtin_amdgcn_fence(__ATOMIC_ACQUIRE, "agent");
    }
    __syncthreads();

    // ---- phase 2: stage c2 (plain coalesced loads; caches invalidated) ----
    for (int q = tid; q < 300; q += NTHR)
        ((float4*)sc)[q] = ((const float4*)c2)[q];
    __syncthreads();

    force_phase(b, tid, lane, wave, sc, sF, ty, ffd, ffa, ffdih, ia, idh);
    __syncthreads();

    // ---- integrate step 2 + final position -> out ----
    if (tid < 12) {
        int t = b*12 + tid;
        float a2 = sF[tid] / mr;
        float v2 = v1r + 0.5f*(a1r + a2)*DT;
        out[t] = sc[t] + v2*DT + 0.5f*a2*DT*DT;      // c3
    }
}

extern "C" void kernel_launch(void* const* d_in, const int* in_sizes, int n_in,
                              void* d_out, int out_size, void* d_ws, size_t ws_size,
                              hipStream_t stream) {
    const float* coords = (const float*)d_in[0];
    const float* vels   = (const float*)d_in[1];
    const float* masses = (const float*)d_in[2];
    const float* ffd    = (const float*)d_in[4];   // ff_distances (4000,140)
    const float* ffa    = (const float*)d_in[5];   // ff_angles (5,20,140)
    const float* ffdih  = (const float*)d_in[6];   // ff_dihedrals (5,20,142)
    const int* iflat    = (const int*)d_in[8];     // inters_flat (160000)
    const int* ia       = (const int*)d_in[9];     // inters_ang (100)
    const int* idh      = (const int*)d_in[10];    // inters_dih (100)
    float* out = (float*)d_out;

    float* c2 = (float*)d_ws;   // 1200 floats: coords after 2nd pos update

    sim_fused<<<NBLK, NTHR, 0, stream>>>(coords, vels, masses, ffd, ffa, ffdih,
                                         iflat, ia, idh, c2, out);
}

// Round 5
// 92.420 us; speedup vs baseline: 1.0216x; 1.0216x over previous
//
#include <hip/hip_runtime.h>
#include <math.h>

#define N_ATOMS 400
#define N_RES   100
#define DT      0.02f
#define PI_D    3.14159265358979323846
#define NBLK    100
#define NTHR    256

// MEASURED (this session, same harness):
//   R2  init+fused, spin barrier + agent-atomic staging : 98.5 us
//   R3  stepA+stepB, kernel-boundary sync               : 92.7 us  <- best
//   R4  single kernel, epoch barrier + agent fences     : 94.4 us
// The kernel boundary is the cheapest grid-wide release/acquire on gfx950
// at this grid size; explicit agent fences (L2 wb + inv across 8 XCDs)
// cost more than the ~1.8 us dispatch node they replace. Keep 2 kernels.

// ---------- small float3 helpers ----------
struct V3 { float x, y, z; };
__device__ __forceinline__ V3 v3(float x, float y, float z) { V3 r{x,y,z}; return r; }
__device__ __forceinline__ V3 sub(V3 a, V3 b) { return v3(a.x-b.x, a.y-b.y, a.z-b.z); }
__device__ __forceinline__ V3 neg(V3 a) { return v3(-a.x, -a.y, -a.z); }
__device__ __forceinline__ V3 scale(V3 a, float s) { return v3(a.x*s, a.y*s, a.z*s); }
__device__ __forceinline__ float dot3(V3 a, V3 b) { return a.x*b.x + a.y*b.y + a.z*b.z; }
__device__ __forceinline__ V3 cross3(V3 a, V3 b) {
    return v3(a.y*b.z - a.z*b.y, a.z*b.x - a.x*b.z, a.x*b.y - a.y*b.x);
}
__device__ __forceinline__ float vnorm(V3 a) {
    float s = dot3(a, a);
    return s > 0.0f ? sqrtf(s) : 0.0f;   // safe_norm semantics
}
__device__ __forceinline__ V3 normalize3(V3 a) {
    float n = fmaxf(vnorm(a), 1e-12f);
    return scale(a, 1.0f/n);
}

// ---------- bin index helpers (uniform grids; argmin == nearest, clamped) ----------
__device__ __forceinline__ int clampi(int i, int lo, int hi) {
    return i < lo ? lo : (i > hi ? hi : i);
}
__device__ __forceinline__ int bin_dist(float d) {
    const float INV = (float)(137.0/14.9);     // linspace(1.0, 15.9, 138)
    return clampi((int)floorf((d - 1.0f)*INV + 0.5f), 0, 137);
}
__device__ __forceinline__ int bin_ang(float a) {
    const float C0  = (float)(PI_D/3.0 + 1.5*((PI_D - PI_D/3.0)/140.0));
    const float INV = (float)(140.0/(PI_D - PI_D/3.0));
    return clampi((int)floorf((a - C0)*INV + 0.5f), 0, 137);
}
__device__ __forceinline__ int bin_dih(float a) {
    const float C0  = (float)(-PI_D + 0.5*(2.0*PI_D/140.0));
    const float INV = (float)(140.0/(2.0*PI_D));
    return clampi((int)floorf((a - C0)*INV + 0.5f), 0, 139);
}

// ---------- bonded-term tables ----------
__constant__ int ANG_I[5][3]   = {{0,1,2},{1,2,0},{2,0,1},{0,1,3},{2,1,3}};
__constant__ int ANG_ACROSS[5] = {0,1,2,0,0};
__constant__ int DIH_I[5][4]   = {{2,0,1,2},{0,1,2,0},{1,2,0,1},{2,0,1,3},{3,1,2,0}};
__constant__ int DIH_ACROSS[5] = {3,1,2,3,1};

__device__ __forceinline__ V3 ldpos(const float* c, int res, int atom) {
    int k = (res*4 + atom)*3;
    return v3(c[k], c[k+1], c[k+2]);
}

// add force f for (res, atom) into this block's LDS force slot IF res == b
__device__ __forceinline__ void addOwn(float* sF, int b, int res, int atom, V3 f) {
    if (res == b) {
        atomicAdd(&sF[atom*3+0], f.x);
        atomicAdd(&sF[atom*3+1], f.y);
        atomicAdd(&sF[atom*3+2], f.z);
    }
}

// Block b evaluates bonded terms at r = b (which=0) and r = b-1 (which=1),
// keeping only contributions that land on residue b. Redundant 2x eval of
// cross-residue terms; total <= 20 tiny term-evals per block.
__device__ __forceinline__ void bonded_own(int u, int b, const float* sc,
                              const float* __restrict__ ffa, const float* __restrict__ ffdih,
                              const int* __restrict__ ia, const int* __restrict__ idh,
                              float* sF) {
    int e = u % 10, which = u / 10;
    int r = b - which;
    if (e < 5) {
        // -------- angles --------
        int across = ANG_ACROSS[e];
        bool valid = which ? (b >= 1 && across != 0)
                           : (across == 0 || b <= N_RES-2);
        if (!valid) return;
        int i1 = ANG_I[e][0], i2 = ANG_I[e][1], i3 = ANG_I[e][2];
        int o2 = (across == 2) ? 1 : 0;
        int o3 = (across != 0) ? 1 : 0;
        V3 p1 = ldpos(sc, r,     i1);
        V3 p2 = ldpos(sc, r+o2,  i2);
        V3 p3 = ldpos(sc, r+o3,  i3);
        V3 ba = sub(p1, p2);
        V3 bc = sub(p3, p2);
        float ban = vnorm(ba), bcn = vnorm(bc);
        float ca = dot3(ba, bc) / (ban*bcn);
        ca = fminf(1.0f, fmaxf(-1.0f, ca));
        float ang = acosf(ca);
        int ind = bin_ang(ang);
        int potr = (across == 2) ? r+1 : r;
        const float* row = ffa + (e*20 + ia[potr])*140;
        float f = 0.5f*(row[ind] - row[ind+2]);
        V3 cr = cross3(ba, bc);
        V3 fa = scale(normalize3(cross3(ba, cr)), f/ban);
        V3 fc = scale(normalize3(neg(cross3(bc, cr))), f/bcn);
        V3 fb = neg(v3(fa.x+fc.x, fa.y+fc.y, fa.z+fc.z));
        addOwn(sF, b, r,     i1, fa);
        addOwn(sF, b, r+o2,  i2, fb);
        addOwn(sF, b, r+o3,  i3, fc);
    } else {
        // -------- dihedrals --------
        int di = e - 5;
        bool valid = which ? (b >= 1) : (b <= N_RES-2);
        if (!valid) return;
        int across = DIH_ACROSS[di];
        int i1 = DIH_I[di][0], i2 = DIH_I[di][1], i3 = DIH_I[di][2], i4 = DIH_I[di][3];
        int o2 = (across == 3) ? 1 : 0;
        int o3 = (across >= 2) ? 1 : 0;
        int o4 = 1;
        V3 p1 = ldpos(sc, r,     i1);
        V3 p2 = ldpos(sc, r+o2,  i2);
        V3 p3 = ldpos(sc, r+o3,  i3);
        V3 p4 = ldpos(sc, r+o4,  i4);
        V3 ab = sub(p2, p1);
        V3 bc = sub(p3, p2);
        V3 cd = sub(p4, p3);
        V3 c1 = cross3(ab, bc);
        V3 c2 = cross3(bc, cd);
        float bcn = vnorm(bc);
        V3 cc = cross3(c1, c2);
        float y = dot3(cc, bc) / bcn;
        float x = dot3(c1, c2);
        float dih = atan2f(y, x);
        int ind = bin_dih(dih);
        int potr = (across == 1) ? r : r+1;
        const float* row = ffdih + (di*20 + idh[potr])*142;
        float f = 0.5f*(row[ind] - row[ind+2]);
        V3 fa = scale(normalize3(neg(c1)), f / vnorm(ab));
        V3 fd = scale(normalize3(c2),      f / vnorm(cd));
        float bsq = bcn*bcn;
        float t1 = dot3(ab, bc)/bsq;
        float t2 = dot3(cd, bc)/bsq;
        V3 fb = v3(-fa.x - t1*fa.x + t2*fd.x,
                   -fa.y - t1*fa.y + t2*fd.y,
                   -fa.z - t1*fa.z + t2*fd.z);
        V3 fc = v3(-fa.x - fb.x - fd.x,
                   -fa.y - fb.y - fd.y,
                   -fa.z - fb.z - fd.z);
        addOwn(sF, b, r,     i1, fa);
        addOwn(sF, b, r+o2,  i2, fb);
        addOwn(sF, b, r+o3,  i3, fc);
        addOwn(sF, b, r+o4,  i4, fd);
    }
}

// Force phase shared by both kernels: bonded (threads 0..19) + pair (one
// wave per own atom, types prefetched in ty[7]); result accumulated in sF[12].
__device__ __forceinline__ void force_phase(int b, int tid, int lane, int wave,
                              const float* sc, float* sF, const int* ty,
                              const float* __restrict__ ffd, const float* __restrict__ ffa,
                              const float* __restrict__ ffdih, const int* __restrict__ ia,
                              const int* __restrict__ idh) {
    if (tid < 20) bonded_own(tid, b, sc, ffa, ffdih, ia, idh, sF);

    int j = b*4 + wave;
    float cx = sc[3*j], cy = sc[3*j+1], cz = sc[3*j+2];
    float fx = 0.0f, fy = 0.0f, fz = 0.0f;
    #pragma unroll
    for (int k = 0; k < 7; ++k) {
        int i = lane + 64*k;
        if (k < 6 || i < N_ATOMS) {
            float dx = cx - sc[3*i];
            float dy = cy - sc[3*i+1];
            float dz = cz - sc[3*i+2];
            float d2 = dx*dx + dy*dy + dz*dz;
            float d  = d2 > 0.0f ? sqrtf(d2) : 0.0f;
            int ind  = bin_dist(d);
            const float* row = ffd + ty[k]*140;
            float f = 0.5f*(row[ind] - row[ind+2]);
            float w = f / fmaxf(d, 0.01f);
            fx += w*dx; fy += w*dy; fz += w*dz;
        }
    }
    #pragma unroll
    for (int off = 32; off > 0; off >>= 1) {
        fx += __shfl_down(fx, off);
        fy += __shfl_down(fy, off);
        fz += __shfl_down(fz, off);
    }
    if (lane == 0) {
        atomicAdd(&sF[wave*3+0], fx);
        atomicAdd(&sF[wave*3+1], fy);
        atomicAdd(&sF[wave*3+2], fz);
    }
}

// Kernel A: every block redundantly computes c1 = cin + vin*DT for ALL
// atoms (elementwise, cheap) directly into LDS -> no init kernel, no
// grid barrier. Staging loads are issued FIRST (they feed __syncthreads,
// the block-wide critical path); the step-invariant iflat prefetch queues
// behind them (not consumed until after the barrier).
__global__ void __launch_bounds__(NTHR)
stepA(const float* __restrict__ cin, const float* __restrict__ vin,
      const float* __restrict__ masses, const float* __restrict__ ffd,
      const float* __restrict__ ffa, const float* __restrict__ ffdih,
      const int* __restrict__ iflat, const int* __restrict__ ia,
      const int* __restrict__ idh, float* __restrict__ c2,
      float* __restrict__ v1, float* __restrict__ a1)
{
    __shared__ float sc[N_ATOMS*3];
    __shared__ float sF[12];
    const int tid  = threadIdx.x;
    const int b    = blockIdx.x;
    const int lane = tid & 63;
    const int wave = tid >> 6;
    const int j    = b*4 + wave;

    // c1 for ALL atoms, float4-vectorized (critical path: feeds the barrier)
    for (int q = tid; q < 300; q += NTHR) {
        float4 cv = ((const float4*)cin)[q];
        float4 vv = ((const float4*)vin)[q];
        float4 r;
        r.x = cv.x + vv.x*DT; r.y = cv.y + vv.y*DT;
        r.z = cv.z + vv.z*DT; r.w = cv.w + vv.w*DT;
        ((float4*)sc)[q] = r;
    }
    if (tid < 12) sF[tid] = 0.0f;

    // pair types (step-invariant; consumed only after the barrier)
    int ty[7];
    #pragma unroll
    for (int k = 0; k < 7; ++k) {
        int i = lane + 64*k;
        ty[k] = (k < 6 || i < N_ATOMS) ? iflat[i*N_ATOMS + j] : 0;
    }
    __syncthreads();

    force_phase(b, tid, lane, wave, sc, sF, ty, ffd, ffa, ffdih, ia, idh);
    __syncthreads();

    if (tid < 12) {
        int t = b*12 + tid;
        float a = sF[tid] / masses[b*4 + tid/3];
        float v = vin[t] + 0.5f*a*DT;                    // a_last = 0
        float cc = sc[t] + v*DT + 0.5f*a*DT*DT;
        c2[t] = cc; v1[t] = v; a1[t] = a;
    }
}

// Kernel B: stage c2 (plain coalesced loads — coherent across the kernel
// boundary), force phase, final integration, write c3 to out.
__global__ void __launch_bounds__(NTHR)
stepB(const float* __restrict__ masses, const float* __restrict__ ffd,
      const float* __restrict__ ffa, const float* __restrict__ ffdih,
      const int* __restrict__ iflat, const int* __restrict__ ia,
      const int* __restrict__ idh, const float* __restrict__ c2,
      const float* __restrict__ v1, const float* __restrict__ a1,
      float* __restrict__ out)
{
    __shared__ float sc[N_ATOMS*3];
    __shared__ float sF[12];
    const int tid  = threadIdx.x;
    const int b    = blockIdx.x;
    const int lane = tid & 63;
    const int wave = tid >> 6;
    const int j    = b*4 + wave;

    // staging first (critical path), types behind it
    for (int q = tid; q < 300; q += NTHR)
        ((float4*)sc)[q] = ((const float4*)c2)[q];
    if (tid < 12) sF[tid] = 0.0f;

    int ty[7];
    #pragma unroll
    for (int k = 0; k < 7; ++k) {
        int i = lane + 64*k;
        ty[k] = (k < 6 || i < N_ATOMS) ? iflat[i*N_ATOMS + j] : 0;
    }
    __syncthreads();

    force_phase(b, tid, lane, wave, sc, sF, ty, ffd, ffa, ffdih, ia, idh);
    __syncthreads();

    if (tid < 12) {
        int t = b*12 + tid;
        float a = sF[tid] / masses[b*4 + tid/3];
        float v = v1[t] + 0.5f*(a1[t] + a)*DT;
        out[t] = sc[t] + v*DT + 0.5f*a*DT*DT;            // c3
    }
}

extern "C" void kernel_launch(void* const* d_in, const int* in_sizes, int n_in,
                              void* d_out, int out_size, void* d_ws, size_t ws_size,
                              hipStream_t stream) {
    const float* coords = (const float*)d_in[0];
    const float* vels   = (const float*)d_in[1];
    const float* masses = (const float*)d_in[2];
    const float* ffd    = (const float*)d_in[4];   // ff_distances (4000,140)
    const float* ffa    = (const float*)d_in[5];   // ff_angles (5,20,140)
    const float* ffdih  = (const float*)d_in[6];   // ff_dihedrals (5,20,142)
    const int* iflat    = (const int*)d_in[8];     // inters_flat (160000)
    const int* ia       = (const int*)d_in[9];     // inters_ang (100)
    const int* idh      = (const int*)d_in[10];    // inters_dih (100)
    float* out = (float*)d_out;

    float* ws = (float*)d_ws;
    float* c2 = ws;          // 1200 floats: coords after 2nd pos update
    float* v1 = ws + 1200;   // 1200 floats: vel after 1st step
    float* a1 = ws + 2400;   // 1200 floats: accel of 1st step

    stepA<<<NBLK, NTHR, 0, stream>>>(coords, vels, masses, ffd, ffa, ffdih,
                                     iflat, ia, idh, c2, v1, a1);
    stepB<<<NBLK, NTHR, 0, stream>>>(masses, ffd, ffa, ffdih,
                                     iflat, ia, idh, c2, v1, a1, out);
}